// Round 1
// baseline (230.602 us; speedup 1.0000x reference)
//
#include <hip/hip_runtime.h>
#include <hip/hip_bf16.h>
#include <stdint.h>

// NTXentLoss: B=4096, D=512, N=8192, tau=0.07, out = scalar mean loss.
// loss_i = -sim[i, i^B] + M + log( sum_{j != i} exp(sim_ij - M) ),  M = 1/tau
// (the reference's two -1e9 mask entries underflow to 0 in logsumexp).

#define N_TOT   8192
#define B_HALF  4096
#define DDIM    512
#define INV_TAU 14.285714285714286f   // 1/0.07 == fixed logsumexp offset M

typedef __bf16 bf16x8 __attribute__((ext_vector_type(8)));
typedef __bf16 bf16x4 __attribute__((ext_vector_type(4)));
typedef float  floatx4 __attribute__((ext_vector_type(4)));

// async global->LDS, 16B per lane; LDS dest must be wave-uniform base (lane*16 auto)
__device__ __forceinline__ void gl2lds16(const void* g, void* l) {
    __builtin_amdgcn_global_load_lds(
        (const __attribute__((address_space(1))) void*)g,
        (__attribute__((address_space(3))) void*)l, 16, 0, 0);
}

// ---------------- kernel 1: normalize rows, fp32 -> bf16 z ----------------
// one wave per row; block = 4 rows
__global__ __launch_bounds__(256) void knorm(const float* __restrict__ anchor,
                                             const float* __restrict__ positive,
                                             __bf16* __restrict__ z) {
    const int row  = blockIdx.x * 4 + (threadIdx.x >> 6);
    const int lane = threadIdx.x & 63;
    const float* src = (row < B_HALF) ? (anchor + (size_t)row * DDIM)
                                      : (positive + (size_t)(row - B_HALF) * DDIM);
    float4 v0 = ((const float4*)src)[lane];
    float4 v1 = ((const float4*)src)[lane + 64];
    float ss = v0.x*v0.x + v0.y*v0.y + v0.z*v0.z + v0.w*v0.w
             + v1.x*v1.x + v1.y*v1.y + v1.z*v1.z + v1.w*v1.w;
    #pragma unroll
    for (int m = 1; m < 64; m <<= 1) ss += __shfl_xor(ss, m, 64);
    const float inv = 1.0f / fmaxf(sqrtf(ss), 1e-8f);
    bf16x4 o0, o1;
    o0[0] = (__bf16)(v0.x*inv); o0[1] = (__bf16)(v0.y*inv);
    o0[2] = (__bf16)(v0.z*inv); o0[3] = (__bf16)(v0.w*inv);
    o1[0] = (__bf16)(v1.x*inv); o1[1] = (__bf16)(v1.y*inv);
    o1[2] = (__bf16)(v1.z*inv); o1[3] = (__bf16)(v1.w*inv);
    bf16x4* dst = (bf16x4*)(z + (size_t)row * DDIM);
    dst[lane]      = o0;
    dst[lane + 64] = o1;
}

// ---------------- kernel 2: sim tile GEMM + fused exp-sum epilogue ----------------
// grid (64 col-tiles, 64 row-tiles); block 256 = 4 waves; each wave 64x64 of C.
// LDS tiles 128x64 bf16, rotation-swizzled: phys_chunk = (logical_chunk + row) & 7
// -> conflict-free ds_read_b128 fragment reads while global_load_lds stays
//    contiguous (wave-uniform base + lane*16).
__global__ __launch_bounds__(256) void ksim(const __bf16* __restrict__ z,
                                            float* __restrict__ row_sums,
                                            float* __restrict__ pos_sims) {
    const int ct = blockIdx.x, rt = blockIdx.y;
    const int r0 = rt * 128, c0 = ct * 128;
    const int tid  = threadIdx.x;
    const int w    = tid >> 6, lane = tid & 63;
    const int quad = lane >> 4, nlo = lane & 15;
    const int wrow = (w >> 1) * 64, wcol = (w & 1) * 64;

    __shared__ __align__(16) char smem[32768];
    char* As = smem;            // 16 KB: A tile (row block)
    char* Bs = smem + 16384;    // 16 KB: B tile (col block)

    floatx4 acc[4][4];
    #pragma unroll
    for (int a = 0; a < 4; a++)
        #pragma unroll
        for (int b = 0; b < 4; b++) acc[a][b] = (floatx4){0.f, 0.f, 0.f, 0.f};

    const int srow = lane >> 3;   // row within an 8-row staging chunk
    const int p    = lane & 7;    // physical 16B chunk within row

    for (int kb = 0; kb < DDIM; kb += 64) {
        #pragma unroll
        for (int it = 0; it < 4; it++) {
            const int c  = w * 4 + it;          // 8-row chunk id, 0..15
            const int rr = c * 8 + srow;        // tile row 0..127
            const int lc = (p - rr) & 7;        // logical chunk stored at phys p
            const __bf16* ga = z + (size_t)(r0 + rr) * DDIM + kb + lc * 8;
            const __bf16* gb = z + (size_t)(c0 + rr) * DDIM + kb + lc * 8;
            gl2lds16(ga, As + c * 1024);
            gl2lds16(gb, Bs + c * 1024);
        }
        __syncthreads();

        #pragma unroll
        for (int ks = 0; ks < 2; ks++) {
            bf16x8 af[4], bfr[4];
            #pragma unroll
            for (int mi = 0; mi < 4; mi++) {
                const int rr = wrow + mi * 16 + nlo;
                const int pc = (ks * 4 + quad + rr) & 7;
                af[mi] = *(const bf16x8*)(As + rr * 128 + pc * 16);
            }
            #pragma unroll
            for (int ni = 0; ni < 4; ni++) {
                const int rr = wcol + ni * 16 + nlo;
                const int pc = (ks * 4 + quad + rr) & 7;
                bfr[ni] = *(const bf16x8*)(Bs + rr * 128 + pc * 16);
            }
            #pragma unroll
            for (int mi = 0; mi < 4; mi++)
                #pragma unroll
                for (int ni = 0; ni < 4; ni++)
                    acc[mi][ni] = __builtin_amdgcn_mfma_f32_16x16x32_bf16(
                        af[mi], bfr[ni], acc[mi][ni], 0, 0, 0);
        }
        __syncthreads();
    }

    // epilogue: C/D layout col = lane&15, row = quad*4 + reg
    #pragma unroll
    for (int mi = 0; mi < 4; mi++) {
        #pragma unroll
        for (int reg = 0; reg < 4; reg++) {
            const int m = quad * 4 + reg;
            const int i = r0 + wrow + mi * 16 + m;
            const int ipos = i ^ B_HALF;
            float s = 0.f;
            #pragma unroll
            for (int ni = 0; ni < 4; ni++) {
                const int j = c0 + wcol + ni * 16 + nlo;
                const float sim = acc[mi][ni][reg] * INV_TAU;
                if (j == ipos) pos_sims[i] = sim;        // unique writer per i
                s += (j == i) ? 0.f : __expf(sim - INV_TAU);
            }
            s += __shfl_xor(s, 1, 64);
            s += __shfl_xor(s, 2, 64);
            s += __shfl_xor(s, 4, 64);
            s += __shfl_xor(s, 8, 64);
            if (nlo == 0) atomicAdd(&row_sums[i], s);
        }
    }
}

// ---------------- kernel 3: loss per row + mean ----------------
__global__ __launch_bounds__(1024) void kfinal(const float* __restrict__ row_sums,
                                               const float* __restrict__ pos_sims,
                                               float* __restrict__ out) {
    const int tid = threadIdx.x;
    float acc = 0.f;
    for (int i = tid; i < N_TOT; i += 1024)
        acc += INV_TAU + __logf(row_sums[i]) - pos_sims[i];
    #pragma unroll
    for (int m = 1; m < 64; m <<= 1) acc += __shfl_xor(acc, m, 64);
    __shared__ float wsum[16];
    if ((tid & 63) == 0) wsum[tid >> 6] = acc;
    __syncthreads();
    if (tid < 16) {
        float v = wsum[tid];
        #pragma unroll
        for (int m = 1; m < 16; m <<= 1) v += __shfl_xor(v, m, 64);
        if (tid == 0) out[0] = v / (float)N_TOT;
    }
}

extern "C" void kernel_launch(void* const* d_in, const int* in_sizes, int n_in,
                              void* d_out, int out_size, void* d_ws, size_t ws_size,
                              hipStream_t stream) {
    const float* anchor   = (const float*)d_in[0];
    const float* positive = (const float*)d_in[1];
    float* out = (float*)d_out;

    char* ws = (char*)d_ws;
    __bf16* z        = (__bf16*)ws;                        // 8192*512*2 = 8 MB
    float*  row_sums = (float*)(ws + 8388608);             // 32 KB
    float*  pos_sims = (float*)(ws + 8388608 + 32768);     // 32 KB

    hipMemsetAsync(row_sums, 0, N_TOT * sizeof(float), stream);
    knorm<<<N_TOT / 4, 256, 0, stream>>>(anchor, positive, z);
    ksim<<<dim3(64, 64), 256, 0, stream>>>(z, row_sums, pos_sims);
    kfinal<<<1, 1024, 0, stream>>>(row_sums, pos_sims, out);
}

// Round 2
// 151.696 us; speedup vs baseline: 1.5202x; 1.5202x over previous
//
#include <hip/hip_runtime.h>
#include <hip/hip_bf16.h>
#include <stdint.h>

// NTXentLoss: B=4096, D=512, N=8192, tau=0.07, out = scalar mean loss.
// loss_i = -sim[i, i^B] + M + log( sum_{j != i} exp(sim_ij - M) ),  M = 1/tau
// (the reference's two -1e9 mask entries underflow to 0 in logsumexp; the pos
//  logit appears exactly once in the concatenated logsumexp, so the sum is
//  simply over all j != i).
//
// R2: exploit sim symmetry — only upper-triangle 128x128 tiles (2080 blocks
// instead of 4096). Off-diagonal tiles contribute exp-sums to BOTH their rows
// (reduce over col-lanes) and their cols (reduce over reg+quad). ~2x FLOP cut
// on the dominant kernel. memset folded into knorm.

#define N_TOT   8192
#define B_HALF  4096
#define DDIM    512
#define INV_TAU 14.285714285714286f   // 1/0.07 == fixed logsumexp offset M

typedef __bf16 bf16x8 __attribute__((ext_vector_type(8)));
typedef __bf16 bf16x4 __attribute__((ext_vector_type(4)));
typedef float  floatx4 __attribute__((ext_vector_type(4)));

__device__ __forceinline__ void gl2lds16(const void* g, void* l) {
    __builtin_amdgcn_global_load_lds(
        (const __attribute__((address_space(1))) void*)g,
        (__attribute__((address_space(3))) void*)l, 16, 0, 0);
}

// ---------------- kernel 1: normalize rows, fp32 -> bf16 z; zero row_sums ----
__global__ __launch_bounds__(256) void knorm(const float* __restrict__ anchor,
                                             const float* __restrict__ positive,
                                             __bf16* __restrict__ z,
                                             float* __restrict__ row_sums) {
    const int row  = blockIdx.x * 4 + (threadIdx.x >> 6);
    const int lane = threadIdx.x & 63;
    if (lane == 0) row_sums[row] = 0.0f;   // replaces hipMemsetAsync
    const float* src = (row < B_HALF) ? (anchor + (size_t)row * DDIM)
                                      : (positive + (size_t)(row - B_HALF) * DDIM);
    float4 v0 = ((const float4*)src)[lane];
    float4 v1 = ((const float4*)src)[lane + 64];
    float ss = v0.x*v0.x + v0.y*v0.y + v0.z*v0.z + v0.w*v0.w
             + v1.x*v1.x + v1.y*v1.y + v1.z*v1.z + v1.w*v1.w;
    #pragma unroll
    for (int m = 1; m < 64; m <<= 1) ss += __shfl_xor(ss, m, 64);
    const float inv = 1.0f / fmaxf(sqrtf(ss), 1e-8f);
    bf16x4 o0, o1;
    o0[0] = (__bf16)(v0.x*inv); o0[1] = (__bf16)(v0.y*inv);
    o0[2] = (__bf16)(v0.z*inv); o0[3] = (__bf16)(v0.w*inv);
    o1[0] = (__bf16)(v1.x*inv); o1[1] = (__bf16)(v1.y*inv);
    o1[2] = (__bf16)(v1.z*inv); o1[3] = (__bf16)(v1.w*inv);
    bf16x4* dst = (bf16x4*)(z + (size_t)row * DDIM);
    dst[lane]      = o0;
    dst[lane + 64] = o1;
}

// ---------------- kernel 2: upper-triangle sim tiles + fused exp-sum ---------
// 1D grid of 2080 = 64*65/2 tile-pairs (rt <= ct). block 256 = 4 waves; each
// wave owns 64x64 of C via 4x4 16x16x32 bf16 fragments, BK=64, rotation-
// swizzled LDS (conflict-free ds_read_b128 while global_load_lds stays
// wave-uniform-base contiguous).
__global__ __launch_bounds__(256) void ksim(const __bf16* __restrict__ z,
                                            float* __restrict__ row_sums,
                                            float* __restrict__ pos_sims) {
    // triangular decode (block-uniform, <=63 scalar iterations)
    int rem = blockIdx.x, rt = 0;
    while (rem >= 64 - rt) { rem -= 64 - rt; rt++; }
    const int ct = rt + rem;
    const bool diag = (rt == ct);
    const bool posb = (ct == rt + 32);

    const int r0 = rt * 128, c0 = ct * 128;
    const int tid  = threadIdx.x;
    const int w    = tid >> 6, lane = tid & 63;
    const int quad = lane >> 4, nlo = lane & 15;
    const int wrow = (w >> 1) * 64, wcol = (w & 1) * 64;

    __shared__ __align__(16) char smem[32768];
    char* As = smem;
    char* Bs = smem + 16384;
    const char* Bbase = diag ? As : Bs;   // diag blocks reuse the A tile

    floatx4 acc[4][4];
    #pragma unroll
    for (int a = 0; a < 4; a++)
        #pragma unroll
        for (int b = 0; b < 4; b++) acc[a][b] = (floatx4){0.f, 0.f, 0.f, 0.f};

    const int srow = lane >> 3;   // row within an 8-row staging chunk
    const int p    = lane & 7;    // physical 16B chunk within row

    for (int kb = 0; kb < DDIM; kb += 64) {
        #pragma unroll
        for (int it = 0; it < 4; it++) {
            const int c  = w * 4 + it;          // 8-row chunk id, 0..15
            const int rr = c * 8 + srow;        // tile row 0..127
            const int lc = (p - rr) & 7;        // logical chunk stored at phys p
            gl2lds16(z + (size_t)(r0 + rr) * DDIM + kb + lc * 8, As + c * 1024);
            if (!diag)
                gl2lds16(z + (size_t)(c0 + rr) * DDIM + kb + lc * 8, Bs + c * 1024);
        }
        __syncthreads();

        #pragma unroll
        for (int ks = 0; ks < 2; ks++) {
            bf16x8 af[4], bfr[4];
            #pragma unroll
            for (int mi = 0; mi < 4; mi++) {
                const int rr = wrow + mi * 16 + nlo;
                const int pc = (ks * 4 + quad + rr) & 7;
                af[mi] = *(const bf16x8*)(As + rr * 128 + pc * 16);
            }
            #pragma unroll
            for (int ni = 0; ni < 4; ni++) {
                const int rr = wcol + ni * 16 + nlo;
                const int pc = (ks * 4 + quad + rr) & 7;
                bfr[ni] = *(const bf16x8*)(Bbase + rr * 128 + pc * 16);
            }
            #pragma unroll
            for (int mi = 0; mi < 4; mi++)
                #pragma unroll
                for (int ni = 0; ni < 4; ni++)
                    acc[mi][ni] = __builtin_amdgcn_mfma_f32_16x16x32_bf16(
                        af[mi], bfr[ni], acc[mi][ni], 0, 0, 0);
        }
        __syncthreads();
    }

    // epilogue: C/D layout col = lane&15, row = quad*4 + reg
    if (diag) {
        #pragma unroll
        for (int mi = 0; mi < 4; mi++) {
            #pragma unroll
            for (int reg = 0; reg < 4; reg++) {
                const int i = r0 + wrow + mi * 16 + quad * 4 + reg;
                float rs = 0.f;
                #pragma unroll
                for (int ni = 0; ni < 4; ni++) {
                    const int j = c0 + wcol + ni * 16 + nlo;
                    const float e = __expf(acc[mi][ni][reg] * INV_TAU - INV_TAU);
                    rs += (j == i) ? 0.f : e;
                }
                rs += __shfl_xor(rs, 1, 64);
                rs += __shfl_xor(rs, 2, 64);
                rs += __shfl_xor(rs, 4, 64);
                rs += __shfl_xor(rs, 8, 64);
                if (nlo == 0) atomicAdd(&row_sums[i], rs);
            }
        }
    } else {
        float cs[4] = {0.f, 0.f, 0.f, 0.f};   // per-lane col partials
        #pragma unroll
        for (int mi = 0; mi < 4; mi++) {
            #pragma unroll
            for (int reg = 0; reg < 4; reg++) {
                const int i = r0 + wrow + mi * 16 + quad * 4 + reg;
                const int ipos = i ^ B_HALF;
                float rs = 0.f;
                #pragma unroll
                for (int ni = 0; ni < 4; ni++) {
                    const int j = c0 + wcol + ni * 16 + nlo;
                    const float sim = acc[mi][ni][reg] * INV_TAU;
                    const float e = __expf(sim - INV_TAU);
                    if (posb && j == ipos) {        // unique writer per pair
                        pos_sims[i] = sim;
                        pos_sims[j] = sim;
                    }
                    rs += e;
                    cs[ni] += e;
                }
                rs += __shfl_xor(rs, 1, 64);
                rs += __shfl_xor(rs, 2, 64);
                rs += __shfl_xor(rs, 4, 64);
                rs += __shfl_xor(rs, 8, 64);
                if (nlo == 0) atomicAdd(&row_sums[i], rs);
            }
        }
        #pragma unroll
        for (int ni = 0; ni < 4; ni++) {
            float c = cs[ni];
            c += __shfl_xor(c, 16, 64);
            c += __shfl_xor(c, 32, 64);
            if (quad == 0)
                atomicAdd(&row_sums[c0 + wcol + ni * 16 + nlo], c);
        }
    }
}

// ---------------- kernel 3: loss per row + mean ----------------
__global__ __launch_bounds__(1024) void kfinal(const float* __restrict__ row_sums,
                                               const float* __restrict__ pos_sims,
                                               float* __restrict__ out) {
    const int tid = threadIdx.x;
    float acc = 0.f;
    for (int i = tid; i < N_TOT; i += 1024)
        acc += INV_TAU + __logf(row_sums[i]) - pos_sims[i];
    #pragma unroll
    for (int m = 1; m < 64; m <<= 1) acc += __shfl_xor(acc, m, 64);
    __shared__ float wsum[16];
    if ((tid & 63) == 0) wsum[tid >> 6] = acc;
    __syncthreads();
    if (tid < 16) {
        float v = wsum[tid];
        #pragma unroll
        for (int m = 1; m < 16; m <<= 1) v += __shfl_xor(v, m, 64);
        if (tid == 0) out[0] = v / (float)N_TOT;
    }
}

extern "C" void kernel_launch(void* const* d_in, const int* in_sizes, int n_in,
                              void* d_out, int out_size, void* d_ws, size_t ws_size,
                              hipStream_t stream) {
    const float* anchor   = (const float*)d_in[0];
    const float* positive = (const float*)d_in[1];
    float* out = (float*)d_out;

    char* ws = (char*)d_ws;
    __bf16* z        = (__bf16*)ws;                        // 8192*512*2 = 8 MB
    float*  row_sums = (float*)(ws + 8388608);             // 32 KB
    float*  pos_sims = (float*)(ws + 8388608 + 32768);     // 32 KB

    knorm<<<N_TOT / 4, 256, 0, stream>>>(anchor, positive, z, row_sums);
    ksim<<<2080, 256, 0, stream>>>(z, row_sums, pos_sims);
    kfinal<<<1, 1024, 0, stream>>>(row_sums, pos_sims, out);
}